// Round 1
// baseline (336.684 us; speedup 1.0000x reference)
//
#include <hip/hip_runtime.h>

typedef unsigned short u16;
typedef unsigned int u32;
typedef __bf16 bf16x8 __attribute__((ext_vector_type(8)));
typedef float floatx4 __attribute__((ext_vector_type(4)));

#define AS1 __attribute__((address_space(1)))
#define AS3 __attribute__((address_space(3)))

__device__ __forceinline__ u16 f2bf(float f) {
    union { float f; u32 u; } a; a.f = f;
    u32 u = a.u;
    u32 r = (u + 0x7fffu + ((u >> 16) & 1u)) >> 16;
    return (u16)r;
}
__device__ __forceinline__ float bf2f(u16 h) {
    union { u32 u; float f; } a; a.u = ((u32)h) << 16; return a.f;
}

// ---------------- fp32 -> bf16 cast, 4 elems/thread ----------------
__global__ void k_f2b(const float* __restrict__ in, u16* __restrict__ out, int n4) {
    int i = blockIdx.x * blockDim.x + threadIdx.x;
    if (i >= n4) return;
    float4 v = reinterpret_cast<const float4*>(in)[i];
    u32 lo = (u32)f2bf(v.x) | ((u32)f2bf(v.y) << 16);
    u32 hi = (u32)f2bf(v.z) | ((u32)f2bf(v.w) << 16);
    reinterpret_cast<uint2*>(out)[i] = make_uint2(lo, hi);
}

// ---------------- RoPE tables: cos/sin [S][64], emb = concat(freqs,freqs) ----------------
__global__ void k_rope_tab(float* __restrict__ ct, float* __restrict__ st) {
    int i = blockIdx.x * blockDim.x + threadIdx.x; // 2048*64
    if (i >= 2048 * 64) return;
    int s = i >> 6, d = i & 63;
    float inv = powf(10000.f, -(float)(d & 31) * (1.f / 32.f));
    float ang = (float)s * inv;
    ct[i] = cosf(ang);
    st[i] = sinf(ang);
}

// ---------------- RoPE in-place on q,k bf16 [B][S][H*64]; pairs (2i,2i+1) ----------------
__global__ void k_rope_apply(u16* __restrict__ q, u16* __restrict__ k,
                             const float* __restrict__ ct, const float* __restrict__ st) {
    int t = blockIdx.x * blockDim.x + threadIdx.x; // 2^21 = B*S*H*32
    int d2 = t & 31; int h = (t >> 5) & 15; int s = (t >> 9) & 2047; int b = t >> 20;
    int d0 = d2 * 2;
    int base = ((b * 2048 + s) * 1024) + h * 64 + d0;
    int tb = s * 64 + d0;
    float c0 = ct[tb], c1 = ct[tb + 1], s0 = st[tb], s1 = st[tb + 1];
    u32 qv = *reinterpret_cast<u32*>(q + base);
    float q0 = bf2f((u16)qv), q1 = bf2f((u16)(qv >> 16));
    float r0 = q0 * c0 - q1 * s0;
    float r1 = q1 * c1 + q0 * s1;
    *reinterpret_cast<u32*>(q + base) = (u32)f2bf(r0) | ((u32)f2bf(r1) << 16);
    u32 kv = *reinterpret_cast<u32*>(k + base);
    float k0 = bf2f((u16)kv), k1 = bf2f((u16)(kv >> 16));
    float t0 = k0 * c0 - k1 * s0;
    float t1 = k1 * c1 + k0 * s1;
    *reinterpret_cast<u32*>(k + base) = (u32)f2bf(t0) | ((u32)f2bf(t1) << 16);
}

// ---------------- GEMM: C[m][n] = sum_k A[m][k]*Bw[n][k] + bias[n] ----------------
// A: MxK bf16 row-major, Bw: NxK bf16 row-major (B^T form). 128x128 tile, BK=32,
// 4 waves (2x2), 4x4 16x16x32 fragments per wave, global_load_lds width-16 staging.
template<int FP32OUT>
__global__ __launch_bounds__(256) void k_gemm_bt(const u16* __restrict__ A, const u16* __restrict__ Bw,
                                                 const float* __restrict__ bias, void* __restrict__ Cout,
                                                 int M, int N, int K) {
    __shared__ __attribute__((aligned(16))) u16 Alds[128 * 32];
    __shared__ __attribute__((aligned(16))) u16 Blds[128 * 32];
    const int tid = threadIdx.x;
    const int w = tid >> 6, lane = tid & 63;
    const int wr = w >> 1, wc = w & 1;
    const int c = lane & 15, g = lane >> 4;
    const int m0 = blockIdx.y * 128, n0 = blockIdx.x * 128;

    floatx4 acc[4][4] = {};

    const int srow = lane >> 2;       // row within 16-row chunk
    const int skc = (lane & 3) * 8;   // k offset (elems)

    for (int k0 = 0; k0 < K; k0 += 32) {
        #pragma unroll
        for (int ch = 0; ch < 2; ch++) {
            int cc = w + ch * 4; // chunk 0..7, wave-uniform
            const u16* ga = A  + (size_t)(m0 + cc * 16 + srow) * K + k0 + skc;
            const u16* gb = Bw + (size_t)(n0 + cc * 16 + srow) * K + k0 + skc;
            __builtin_amdgcn_global_load_lds((AS1 void*)(ga), (AS3 void*)(Alds + cc * 512), 16, 0, 0);
            __builtin_amdgcn_global_load_lds((AS1 void*)(gb), (AS3 void*)(Blds + cc * 512), 16, 0, 0);
        }
        __syncthreads();
        bf16x8 af[4], bfr[4];
        #pragma unroll
        for (int mi = 0; mi < 4; mi++)
            af[mi] = *reinterpret_cast<const bf16x8*>(Alds + (wr * 64 + mi * 16 + c) * 32 + g * 8);
        #pragma unroll
        for (int ni = 0; ni < 4; ni++)
            bfr[ni] = *reinterpret_cast<const bf16x8*>(Blds + (wc * 64 + ni * 16 + c) * 32 + g * 8);
        #pragma unroll
        for (int mi = 0; mi < 4; mi++)
            #pragma unroll
            for (int ni = 0; ni < 4; ni++)
                acc[mi][ni] = __builtin_amdgcn_mfma_f32_16x16x32_bf16(af[mi], bfr[ni], acc[mi][ni], 0, 0, 0);
        __syncthreads();
    }

    #pragma unroll
    for (int ni = 0; ni < 4; ni++) {
        int col = n0 + wc * 64 + ni * 16 + c;
        float bv = bias[col];
        #pragma unroll
        for (int mi = 0; mi < 4; mi++) {
            #pragma unroll
            for (int i = 0; i < 4; i++) {
                int row = m0 + wr * 64 + mi * 16 + g * 4 + i;
                float v = acc[mi][ni][i] + bv;
                if (FP32OUT) reinterpret_cast<float*>(Cout)[(size_t)row * N + col] = v;
                else         reinterpret_cast<u16*>(Cout)[(size_t)row * N + col] = f2bf(v);
            }
        }
    }
}

// ---------------- Flash attention, causal. Q/K/V bf16 [B][S][H*64], O bf16 same layout.
// grid: (S/64, B*H); 4 independent waves/block, each owns 16 q-rows; KV tile = 32.
__global__ __launch_bounds__(256) void k_attn(const u16* __restrict__ Q, const u16* __restrict__ K,
                                              const u16* __restrict__ V, u16* __restrict__ O) {
    __shared__ __attribute__((aligned(16))) u16 Plds[4][16 * 48]; // per-wave P tile, stride 48
    const int w = threadIdx.x >> 6, lane = threadIdx.x & 63;
    const int c = lane & 15, g = lane >> 4;
    const int bh = blockIdx.y;
    const int b = bh >> 4, h = bh & 15;
    const int qw0 = blockIdx.x * 64 + w * 16;
    const int rowb = b * 2048;
    const int colb = h * 64;

    bf16x8 qf[2];
    #pragma unroll
    for (int db = 0; db < 2; db++)
        qf[db] = *reinterpret_cast<const bf16x8*>(Q + (rowb + qw0 + c) * 1024 + colb + g * 8 + db * 32);

    float m[4], ls[4];
    floatx4 acc[4] = {};
    #pragma unroll
    for (int i = 0; i < 4; i++) { m[i] = -1e30f; ls[i] = 0.f; }

    const int nt = (qw0 + 47) >> 5; // covers kv <= qw0+15
    for (int t = 0; t < nt; t++) {
        const int kv0 = t * 32;
        floatx4 s4[2] = {};
        #pragma unroll
        for (int cb = 0; cb < 2; cb++)
            #pragma unroll
            for (int db = 0; db < 2; db++) {
                bf16x8 kf = *reinterpret_cast<const bf16x8*>(
                    K + (rowb + kv0 + cb * 16 + c) * 1024 + colb + g * 8 + db * 32);
                s4[cb] = __builtin_amdgcn_mfma_f32_16x16x32_bf16(qf[db], kf, s4[cb], 0, 0, 0);
            }
        float p[2][4];
        const bool need_mask = (kv0 + 31 > qw0);
        #pragma unroll
        for (int cb = 0; cb < 2; cb++)
            #pragma unroll
            for (int i = 0; i < 4; i++) {
                float sv = s4[cb][i] * 0.125f;
                if (need_mask && (kv0 + cb * 16 + c > qw0 + g * 4 + i)) sv = -1e30f;
                p[cb][i] = sv;
            }
        #pragma unroll
        for (int i = 0; i < 4; i++) {
            float rm = fmaxf(p[0][i], p[1][i]);
            #pragma unroll
            for (int off = 1; off < 16; off <<= 1)
                rm = fmaxf(rm, __shfl_xor(rm, off));
            float mn = fmaxf(m[i], rm);
            float corr = __expf(m[i] - mn);
            m[i] = mn;
            float p0 = __expf(p[0][i] - mn);
            float p1 = __expf(p[1][i] - mn);
            p[0][i] = p0; p[1][i] = p1;
            float ps = p0 + p1;
            #pragma unroll
            for (int off = 1; off < 16; off <<= 1)
                ps += __shfl_xor(ps, off);
            ls[i] = ls[i] * corr + ps;
            #pragma unroll
            for (int vb = 0; vb < 4; vb++)
                acc[vb][i] = acc[vb][i] * corr;
        }
        // P (C-layout) -> LDS -> A-layout fragment
        #pragma unroll
        for (int cb = 0; cb < 2; cb++)
            #pragma unroll
            for (int i = 0; i < 4; i++)
                Plds[w][(g * 4 + i) * 48 + cb * 16 + c] = f2bf(p[cb][i]);
        asm volatile("s_waitcnt lgkmcnt(0)" ::: "memory");
        bf16x8 pf = *reinterpret_cast<const bf16x8*>(&Plds[w][c * 48 + g * 8]);
        #pragma unroll
        for (int vb = 0; vb < 4; vb++) {
            union { u16 u[8]; bf16x8 v; } vf;
            #pragma unroll
            for (int j = 0; j < 8; j++)
                vf.u[j] = V[(rowb + kv0 + g * 8 + j) * 1024 + colb + vb * 16 + c];
            acc[vb] = __builtin_amdgcn_mfma_f32_16x16x32_bf16(pf, vf.v, acc[vb], 0, 0, 0);
        }
    }
    #pragma unroll
    for (int i = 0; i < 4; i++) {
        float inv = 1.f / ls[i];
        #pragma unroll
        for (int vb = 0; vb < 4; vb++) {
            int orow = rowb + qw0 + g * 4 + i;
            int ocol = colb + vb * 16 + c;
            O[orow * 1024 + ocol] = f2bf(acc[vb][i] * inv);
        }
    }
}

extern "C" void kernel_launch(void* const* d_in, const int* in_sizes, int n_in,
                              void* d_out, int out_size, void* d_ws, size_t ws_size,
                              hipStream_t stream) {
    const float* x  = (const float*)d_in[0];
    const float* wq = (const float*)d_in[1];
    const float* bq = (const float*)d_in[2];
    const float* wk = (const float*)d_in[3];
    const float* bk = (const float*)d_in[4];
    const float* wv = (const float*)d_in[5];
    const float* bv = (const float*)d_in[6];
    const float* wo = (const float*)d_in[7];
    const float* bo = (const float*)d_in[8];

    char* ws = (char*)d_ws;
    u16* xb  = (u16*)(ws);                      // 8 MiB  [4096][1024] bf16
    u16* wqb = (u16*)(ws + (8ull  << 20));      // 2 MiB
    u16* wkb = (u16*)(ws + (10ull << 20));
    u16* wvb = (u16*)(ws + (12ull << 20));
    u16* wob = (u16*)(ws + (14ull << 20));
    u16* qg  = (u16*)(ws + (16ull << 20));      // 8 MiB each
    u16* kg  = (u16*)(ws + (24ull << 20));
    u16* vg  = (u16*)(ws + (32ull << 20));
    u16* og  = (u16*)(ws + (40ull << 20));
    float* ct = (float*)(ws + (48ull << 20));   // 512 KiB
    float* st = (float*)(ws + (49ull << 20));   // 512 KiB

    // casts
    k_f2b<<<4096, 256, 0, stream>>>(x,  xb,  1048576);
    k_f2b<<<1024, 256, 0, stream>>>(wq, wqb, 262144);
    k_f2b<<<1024, 256, 0, stream>>>(wk, wkb, 262144);
    k_f2b<<<1024, 256, 0, stream>>>(wv, wvb, 262144);
    k_f2b<<<1024, 256, 0, stream>>>(wo, wob, 262144);
    k_rope_tab<<<512, 256, 0, stream>>>(ct, st);

    dim3 gg(8, 32); // N/128, M/128
    k_gemm_bt<0><<<gg, 256, 0, stream>>>(xb, wqb, bq, qg, 4096, 1024, 1024);
    k_gemm_bt<0><<<gg, 256, 0, stream>>>(xb, wkb, bk, kg, 4096, 1024, 1024);
    k_gemm_bt<0><<<gg, 256, 0, stream>>>(xb, wvb, bv, vg, 4096, 1024, 1024);

    k_rope_apply<<<8192, 256, 0, stream>>>(qg, kg, ct, st);

    dim3 ga(32, 32); // S/64, B*H
    k_attn<<<ga, 256, 0, stream>>>(qg, kg, vg, og);

    k_gemm_bt<1><<<gg, 256, 0, stream>>>(og, wob, bo, (float*)d_out, 4096, 1024, 1024);
}